// Round 18
// baseline (123.186 us; speedup 1.0000x reference)
//
#include <hip/hip_runtime.h>
#include <math.h>

// RiemannianMetric: g[b,s,i,j] = sum_r tanh(x·W[r]+b[r])^2 A[r,i]A[r,j] + lam*I
// B=2 S=1024 DIM=256 RANK=32. Output 537 MB f32 -> store floor ~80us @6.7TB/s.
// R18: R17 dense 1KB-row stores + occupancy recovered via 1-WAVE BLOCKS.
// 16KB stage/wave caps LDS occupancy at 10 waves/CU; 64-thread blocks reach it
// (R17's 4-wave/64KB blocks: only 8). grid = 4*n_pos, block = contiguous 64KB
// quarter-position (R16 proved quarter-split is free). Zero intra-block coupling.

constexpr int DIM = 256;

typedef float f32x4 __attribute__((ext_vector_type(4)));
typedef short s16x8 __attribute__((ext_vector_type(8))); // 8 bf16 = 4 VGPR

static __device__ __forceinline__ unsigned short f2bf(float f) {
    unsigned int u = __builtin_bit_cast(unsigned int, f);
    u = (u + 0x7FFFu + ((u >> 16) & 1u)) >> 16; // RNE
    return (unsigned short)u;
}
static __device__ __forceinline__ float bf2f(unsigned short s) {
    return __builtin_bit_cast(float, (unsigned int)s << 16);
}

// ---------------- Kernel 1: sw2 (tanh^2) + one-time A bf16 slabs -------------
__global__ __launch_bounds__(256) void build_sw2_kernel(
    const float* __restrict__ x, const float* __restrict__ A,
    const float* __restrict__ W, const float* __restrict__ bvec,
    float* __restrict__ sw2, unsigned short* __restrict__ ab16, int n_pos)
{
    const int tid = threadIdx.x, b = blockIdx.x;

    if (b == n_pos) { // ab16[kg][j][e] = bf16(A[kg*8+e][j])
        #pragma unroll
        for (int kg = 0; kg < 4; ++kg) {
            s16x8 pk;
            #pragma unroll
            for (int e = 0; e < 8; ++e)
                pk[e] = (short)f2bf(A[(kg * 8 + e) * DIM + tid]);
            *(s16x8*)&ab16[((size_t)kg * DIM + tid) * 8] = pk;
        }
        return;
    }

    __shared__ float xs[DIM];
    xs[tid] = x[(size_t)b * DIM + tid];
    __syncthreads();

    const int r = tid >> 3, seg = tid & 7;
    const f32x4* wr4 = (const f32x4*)(W + r * DIM + seg * 32);
    const f32x4* xr4 = (const f32x4*)(xs + seg * 32);
    float dot = 0.f;
    #pragma unroll
    for (int qq = 0; qq < 8; ++qq) {
        f32x4 wv = wr4[qq], xv = xr4[qq];
        dot = fmaf(wv.x, xv.x, dot);
        dot = fmaf(wv.y, xv.y, dot);
        dot = fmaf(wv.z, xv.z, dot);
        dot = fmaf(wv.w, xv.w, dot);
    }
    dot += __shfl_xor(dot, 1);
    dot += __shfl_xor(dot, 2);
    dot += __shfl_xor(dot, 4);
    if (seg == 0) {
        float m = tanhf(dot + bvec[r]);
        sw2[(size_t)b * 32 + r] = m * m;
    }
}

// ---------------- Kernel 2: 1-wave quarter-position dense-row streamer -------
// block bid: pos = bid>>2, quarter q = bid&3; rows q*64..q*64+63 (contig 64KB).
__global__ __launch_bounds__(64) void store_g_wave(
    const unsigned short* __restrict__ ab16, // [4][256][8] plain A bf16
    const float* __restrict__ sw2,           // [n_pos][32]
    const float* __restrict__ log_lambda,
    float* __restrict__ out)
{
    __shared__ alignas(16) float sbuf[16 * 256]; // 16KB, wave-private

    const int lane = threadIdx.x;
    const int bid  = blockIdx.x;
    const int pos  = bid >> 2;
    const int q    = bid & 3;
    const int kg   = lane >> 4, cl = lane & 15;

    const unsigned short* abase = ab16 + (size_t)kg * DIM * 8;

    // per-position scale w2[kg*8+e] (L2-resident)
    const float* w2p = sw2 + (size_t)pos * 32 + kg * 8;
    f32x4 w2lo = *(const f32x4*)w2p;
    f32x4 w2hi = *(const f32x4*)(w2p + 4);
    float w2v[8] = {w2lo.x, w2lo.y, w2lo.z, w2lo.w, w2hi.x, w2hi.y, w2hi.z, w2hi.w};

    // afr[t]: scaled row-tile frags for tiles T = q*4+t (rows T*16+cl)
    s16x8 afr[4];
    #pragma unroll
    for (int t = 0; t < 4; ++t) {
        s16x8 ar = *(const s16x8*)&abase[(size_t)((q * 4 + t) * 16 + cl) * 8];
        #pragma unroll
        for (int e = 0; e < 8; ++e)
            afr[t][e] = (short)f2bf(w2v[e] * bf2f((unsigned short)ar[e]));
    }

    // bfr: all 16 plain-A col-tile frags (L1-hot)
    s16x8 bfr[16];
    #pragma unroll
    for (int u = 0; u < 16; ++u)
        bfr[u] = *(const s16x8*)&abase[(size_t)(u * 16 + cl) * 8];

    const float lam = expf(log_lambda[0]);
    const bool on_diag_lane = (kg == (cl >> 2));
    const int  diag_slot    = cl & 3;

    // write: row=cl, col=u*16+4kg; swz ^((cl&7)<<2). read: full 1KB row / instr.
    const int wbase = cl * 256 + 4 * kg;
    const int wswz  = (cl & 7) << 2;
    const int rcol  = lane * 4;

    float* gbase = out + (size_t)pos * DIM * DIM;

    #pragma unroll 1
    for (int t = 0; t < 4; ++t) {
        const int T = q * 4 + t;
        // 16 MFMAs -> full 16x256 tile into swizzled stage
        #pragma unroll
        for (int u = 0; u < 16; ++u) {
            f32x4 acc = (f32x4)(0.f);
            acc = __builtin_amdgcn_mfma_f32_16x16x32_bf16(bfr[u], afr[t], acc, 0, 0, 0);
            if (u == T && on_diag_lane) // diagonal tile of G
                acc[diag_slot] += lam;
            *(f32x4*)&sbuf[(wbase + u * 16) ^ wswz] = acc;
        }
        // 16 full-row reads -> 16 contiguous 1KB nt stores = dense 16KB span
        float* trow = gbase + (size_t)(T * 16) * DIM;
        #pragma unroll
        for (int m = 0; m < 16; ++m) {
            f32x4 v = *(const f32x4*)&sbuf[(m * 256 + rcol) ^ ((m & 7) << 2)];
            __builtin_nontemporal_store(v, (f32x4*)(trow + (size_t)m * DIM + rcol));
        }
    }
}

// ---------------- Fallback monolith (R7-validated) ---------------------------
__global__ __launch_bounds__(256, 2) void riemannian_metric_fallback(
    const float* __restrict__ x, const float* __restrict__ A,
    const float* __restrict__ log_lambda, const float* __restrict__ W,
    const float* __restrict__ bvec, float* __restrict__ out)
{
    __shared__ float xs[DIM];
    __shared__ float sw[32];
    __shared__ alignas(16) unsigned short vt[4][DIM][8];
    __shared__ alignas(16) float stage[4][16 * 128];

    const int tid  = threadIdx.x;
    const int pos  = blockIdx.x;
    const int lane = tid & 63;
    const int rs   = tid >> 6;

    xs[tid] = x[(size_t)pos * DIM + tid];
    __syncthreads();
    {
        const int r = tid >> 3, seg = tid & 7;
        const f32x4* wr4 = (const f32x4*)(W + r * DIM + seg * 32);
        const f32x4* xr4 = (const f32x4*)(xs + seg * 32);
        float dot = 0.f;
        #pragma unroll
        for (int qq = 0; qq < 8; ++qq) {
            f32x4 wv = wr4[qq], xv = xr4[qq];
            dot = fmaf(wv.x, xv.x, dot);
            dot = fmaf(wv.y, xv.y, dot);
            dot = fmaf(wv.z, xv.z, dot);
            dot = fmaf(wv.w, xv.w, dot);
        }
        dot += __shfl_xor(dot, 1);
        dot += __shfl_xor(dot, 2);
        dot += __shfl_xor(dot, 4);
        if (seg == 0) sw[r] = tanhf(dot + bvec[r]);
    }
    __syncthreads();
    #pragma unroll
    for (int g = 0; g < 4; ++g) {
        s16x8 pk;
        #pragma unroll
        for (int e = 0; e < 8; ++e) {
            const int k = g * 8 + e;
            pk[e] = (short)f2bf(sw[k] * A[k * DIM + tid]);
        }
        *(s16x8*)&vt[g][tid][0] = pk;
    }
    __syncthreads();

    const int kg = lane >> 4, cl = lane & 15;
    s16x8 bfr[16];
    #pragma unroll
    for (int u = 0; u < 16; ++u)
        bfr[u] = *(const s16x8*)&vt[kg][u * 16 + cl][0];
    s16x8 afr[4];
    #pragma unroll
    for (int t = 0; t < 4; ++t)
        afr[t] = *(const s16x8*)&vt[kg][rs * 64 + t * 16 + cl][0];

    const float lam = expf(log_lambda[0]);
    const bool on_diag_lane = (kg == (cl >> 2));
    const int  diag_slot    = cl & 3;

    float* sbuf = stage[rs];
    const int wbase = cl * 128 + 4 * kg;
    const int wswz  = (cl & 7) << 2;
    const int rrow0 = lane >> 5;
    const int rcol  = (lane & 31) * 4;
    float* gbase = out + (size_t)pos * DIM * DIM;

    #pragma unroll 1
    for (int t = 0; t < 4; ++t) {
        #pragma unroll 1
        for (int half = 0; half < 2; ++half) {
            #pragma unroll
            for (int uu = 0; uu < 8; ++uu) {
                const int u = half * 8 + uu;
                f32x4 acc = (f32x4)(0.f);
                acc = __builtin_amdgcn_mfma_f32_16x16x32_bf16(bfr[u], afr[t], acc, 0, 0, 0);
                if (u == rs * 4 + t && on_diag_lane)
                    acc[diag_slot] += lam;
                *(f32x4*)&sbuf[(wbase + uu * 16) ^ wswz] = acc;
            }
            #pragma unroll
            for (int m = 0; m < 8; ++m) {
                const int row = 2 * m + rrow0;
                f32x4 v = *(const f32x4*)&sbuf[(row * 128 + rcol) ^ ((row & 7) << 2)];
                float* gp = gbase + (size_t)(rs * 64 + t * 16 + row) * DIM
                                  + half * 128 + rcol;
                __builtin_nontemporal_store(v, (f32x4*)gp);
            }
        }
    }
}

extern "C" void kernel_launch(void* const* d_in, const int* in_sizes, int n_in,
                              void* d_out, int out_size, void* d_ws, size_t ws_size,
                              hipStream_t stream) {
    const float* x          = (const float*)d_in[0];
    const float* A          = (const float*)d_in[1];
    const float* log_lambda = (const float*)d_in[2];
    const float* W          = (const float*)d_in[3];
    const float* bvec       = (const float*)d_in[4];
    float* out              = (float*)d_out;

    const int n_pos = in_sizes[0] / DIM; // B*S = 2048
    const size_t ab16_bytes = (size_t)4 * DIM * 8 * sizeof(unsigned short);
    const size_t need = ab16_bytes + (size_t)n_pos * 32 * sizeof(float);

    if (ws_size >= need) {
        unsigned short* ab16 = (unsigned short*)d_ws;
        float* sw2 = (float*)((char*)d_ws + ab16_bytes);
        build_sw2_kernel<<<n_pos + 1, 256, 0, stream>>>(x, A, W, bvec, sw2, ab16, n_pos);
        store_g_wave<<<n_pos * 4, 64, 0, stream>>>(ab16, sw2, log_lambda, out);
    } else {
        riemannian_metric_fallback<<<n_pos, 256, 0, stream>>>(x, A, log_lambda, W, bvec, out);
    }
}

// Round 19
// 119.829 us; speedup vs baseline: 1.0280x; 1.0280x over previous
//
#include <hip/hip_runtime.h>
#include <math.h>

// RiemannianMetric: g[b,s,i,j] = sum_r tanh(x·W[r]+b[r])^2 A[r,i]A[r,j] + lam*I
// B=2 S=1024 DIM=256 RANK=32. Output 537 MB f32 -> store floor ~80us @6.7TB/s.
// R19: R17 dense-row pipeline at 2-WAVE blocks. Bracket: 8 waves/CU (R17,4-wave
// blocks)=114; "10" via 1-wave blocks (R18)=123 (block-granularity overhead);
// 20 waves half-density (R13)=118. This round: 32KB/block -> 5 blocks/CU ->
// 10 waves/CU with multi-wave blocks. Per-wave code byte-identical to R17.
// Block = half position (contig 128KB), wave rs owns tiles h*8+rs*4+t.

constexpr int DIM = 256;

typedef float f32x4 __attribute__((ext_vector_type(4)));
typedef short s16x8 __attribute__((ext_vector_type(8))); // 8 bf16 = 4 VGPR

static __device__ __forceinline__ unsigned short f2bf(float f) {
    unsigned int u = __builtin_bit_cast(unsigned int, f);
    u = (u + 0x7FFFu + ((u >> 16) & 1u)) >> 16; // RNE
    return (unsigned short)u;
}
static __device__ __forceinline__ float bf2f(unsigned short s) {
    return __builtin_bit_cast(float, (unsigned int)s << 16);
}

// ---------------- Kernel 1: sw2 (tanh^2) + one-time A bf16 slabs -------------
__global__ __launch_bounds__(256) void build_sw2_kernel(
    const float* __restrict__ x, const float* __restrict__ A,
    const float* __restrict__ W, const float* __restrict__ bvec,
    float* __restrict__ sw2, unsigned short* __restrict__ ab16, int n_pos)
{
    const int tid = threadIdx.x, b = blockIdx.x;

    if (b == n_pos) { // ab16[kg][j][e] = bf16(A[kg*8+e][j])
        #pragma unroll
        for (int kg = 0; kg < 4; ++kg) {
            s16x8 pk;
            #pragma unroll
            for (int e = 0; e < 8; ++e)
                pk[e] = (short)f2bf(A[(kg * 8 + e) * DIM + tid]);
            *(s16x8*)&ab16[((size_t)kg * DIM + tid) * 8] = pk;
        }
        return;
    }

    __shared__ float xs[DIM];
    xs[tid] = x[(size_t)b * DIM + tid];
    __syncthreads();

    const int r = tid >> 3, seg = tid & 7;
    const f32x4* wr4 = (const f32x4*)(W + r * DIM + seg * 32);
    const f32x4* xr4 = (const f32x4*)(xs + seg * 32);
    float dot = 0.f;
    #pragma unroll
    for (int qq = 0; qq < 8; ++qq) {
        f32x4 wv = wr4[qq], xv = xr4[qq];
        dot = fmaf(wv.x, xv.x, dot);
        dot = fmaf(wv.y, xv.y, dot);
        dot = fmaf(wv.z, xv.z, dot);
        dot = fmaf(wv.w, xv.w, dot);
    }
    dot += __shfl_xor(dot, 1);
    dot += __shfl_xor(dot, 2);
    dot += __shfl_xor(dot, 4);
    if (seg == 0) {
        float m = tanhf(dot + bvec[r]);
        sw2[(size_t)b * 32 + r] = m * m;
    }
}

// ---------------- Kernel 2: 2-wave half-position dense-row streamer ----------
// block bid: pos = bid>>1, half h = bid&1; wave rs owns tiles h*8 + rs*4 + t.
__global__ __launch_bounds__(128) void store_g_half(
    const unsigned short* __restrict__ ab16, // [4][256][8] plain A bf16
    const float* __restrict__ sw2,           // [n_pos][32]
    const float* __restrict__ log_lambda,
    float* __restrict__ out)
{
    __shared__ alignas(16) float stage[2][16 * 256]; // 16KB per wave, 32KB total

    const int tid  = threadIdx.x;
    const int bid  = blockIdx.x;
    const int pos  = bid >> 1;
    const int h    = bid & 1;
    const int lane = tid & 63;
    const int rs   = tid >> 6;          // wave 0/1
    const int kg   = lane >> 4, cl = lane & 15;

    const unsigned short* abase = ab16 + (size_t)kg * DIM * 8;

    // per-position scale w2[kg*8+e] (L2-resident)
    const float* w2p = sw2 + (size_t)pos * 32 + kg * 8;
    f32x4 w2lo = *(const f32x4*)w2p;
    f32x4 w2hi = *(const f32x4*)(w2p + 4);
    float w2v[8] = {w2lo.x, w2lo.y, w2lo.z, w2lo.w, w2hi.x, w2hi.y, w2hi.z, w2hi.w};

    // afr[t]: scaled row-tile frags for tiles T = h*8 + rs*4 + t
    s16x8 afr[4];
    #pragma unroll
    for (int t = 0; t < 4; ++t) {
        s16x8 ar = *(const s16x8*)&abase[(size_t)((h * 8 + rs * 4 + t) * 16 + cl) * 8];
        #pragma unroll
        for (int e = 0; e < 8; ++e)
            afr[t][e] = (short)f2bf(w2v[e] * bf2f((unsigned short)ar[e]));
    }

    // bfr: all 16 plain-A col-tile frags (L1-hot)
    s16x8 bfr[16];
    #pragma unroll
    for (int u = 0; u < 16; ++u)
        bfr[u] = *(const s16x8*)&abase[(size_t)(u * 16 + cl) * 8];

    const float lam = expf(log_lambda[0]);
    const bool on_diag_lane = (kg == (cl >> 2));
    const int  diag_slot    = cl & 3;

    float* sbuf = stage[rs];
    const int wbase = cl * 256 + 4 * kg;   // write: row=cl, col=u*16+4kg
    const int wswz  = (cl & 7) << 2;
    const int rcol  = lane * 4;            // read: full 1KB row / instruction

    float* gbase = out + (size_t)pos * DIM * DIM;

    #pragma unroll 1
    for (int t = 0; t < 4; ++t) {
        const int T = h * 8 + rs * 4 + t;
        // 16 MFMAs -> full 16x256 tile into swizzled stage
        #pragma unroll
        for (int u = 0; u < 16; ++u) {
            f32x4 acc = (f32x4)(0.f);
            acc = __builtin_amdgcn_mfma_f32_16x16x32_bf16(bfr[u], afr[t], acc, 0, 0, 0);
            if (u == T && on_diag_lane) // diagonal tile of G
                acc[diag_slot] += lam;
            *(f32x4*)&sbuf[(wbase + u * 16) ^ wswz] = acc;
        }
        // 16 full-row reads -> 16 contiguous 1KB nt stores = dense 16KB span
        float* trow = gbase + (size_t)(T * 16) * DIM;
        #pragma unroll
        for (int m = 0; m < 16; ++m) {
            f32x4 v = *(const f32x4*)&sbuf[(m * 256 + rcol) ^ ((m & 7) << 2)];
            __builtin_nontemporal_store(v, (f32x4*)(trow + (size_t)m * DIM + rcol));
        }
    }
}

// ---------------- Fallback monolith (R7-validated) ---------------------------
__global__ __launch_bounds__(256, 2) void riemannian_metric_fallback(
    const float* __restrict__ x, const float* __restrict__ A,
    const float* __restrict__ log_lambda, const float* __restrict__ W,
    const float* __restrict__ bvec, float* __restrict__ out)
{
    __shared__ float xs[DIM];
    __shared__ float sw[32];
    __shared__ alignas(16) unsigned short vt[4][DIM][8];
    __shared__ alignas(16) float stage[4][16 * 128];

    const int tid  = threadIdx.x;
    const int pos  = blockIdx.x;
    const int lane = tid & 63;
    const int rs   = tid >> 6;

    xs[tid] = x[(size_t)pos * DIM + tid];
    __syncthreads();
    {
        const int r = tid >> 3, seg = tid & 7;
        const f32x4* wr4 = (const f32x4*)(W + r * DIM + seg * 32);
        const f32x4* xr4 = (const f32x4*)(xs + seg * 32);
        float dot = 0.f;
        #pragma unroll
        for (int qq = 0; qq < 8; ++qq) {
            f32x4 wv = wr4[qq], xv = xr4[qq];
            dot = fmaf(wv.x, xv.x, dot);
            dot = fmaf(wv.y, xv.y, dot);
            dot = fmaf(wv.z, xv.z, dot);
            dot = fmaf(wv.w, xv.w, dot);
        }
        dot += __shfl_xor(dot, 1);
        dot += __shfl_xor(dot, 2);
        dot += __shfl_xor(dot, 4);
        if (seg == 0) sw[r] = tanhf(dot + bvec[r]);
    }
    __syncthreads();
    #pragma unroll
    for (int g = 0; g < 4; ++g) {
        s16x8 pk;
        #pragma unroll
        for (int e = 0; e < 8; ++e) {
            const int k = g * 8 + e;
            pk[e] = (short)f2bf(sw[k] * A[k * DIM + tid]);
        }
        *(s16x8*)&vt[g][tid][0] = pk;
    }
    __syncthreads();

    const int kg = lane >> 4, cl = lane & 15;
    s16x8 bfr[16];
    #pragma unroll
    for (int u = 0; u < 16; ++u)
        bfr[u] = *(const s16x8*)&vt[kg][u * 16 + cl][0];
    s16x8 afr[4];
    #pragma unroll
    for (int t = 0; t < 4; ++t)
        afr[t] = *(const s16x8*)&vt[kg][rs * 64 + t * 16 + cl][0];

    const float lam = expf(log_lambda[0]);
    const bool on_diag_lane = (kg == (cl >> 2));
    const int  diag_slot    = cl & 3;

    float* sbuf = stage[rs];
    const int wbase = cl * 128 + 4 * kg;
    const int wswz  = (cl & 7) << 2;
    const int rrow0 = lane >> 5;
    const int rcol  = (lane & 31) * 4;
    float* gbase = out + (size_t)pos * DIM * DIM;

    #pragma unroll 1
    for (int t = 0; t < 4; ++t) {
        #pragma unroll 1
        for (int half = 0; half < 2; ++half) {
            #pragma unroll
            for (int uu = 0; uu < 8; ++uu) {
                const int u = half * 8 + uu;
                f32x4 acc = (f32x4)(0.f);
                acc = __builtin_amdgcn_mfma_f32_16x16x32_bf16(bfr[u], afr[t], acc, 0, 0, 0);
                if (u == rs * 4 + t && on_diag_lane)
                    acc[diag_slot] += lam;
                *(f32x4*)&sbuf[(wbase + uu * 16) ^ wswz] = acc;
            }
            #pragma unroll
            for (int m = 0; m < 8; ++m) {
                const int row = 2 * m + rrow0;
                f32x4 v = *(const f32x4*)&sbuf[(row * 128 + rcol) ^ ((row & 7) << 2)];
                float* gp = gbase + (size_t)(rs * 64 + t * 16 + row) * DIM
                                  + half * 128 + rcol;
                __builtin_nontemporal_store(v, (f32x4*)gp);
            }
        }
    }
}

extern "C" void kernel_launch(void* const* d_in, const int* in_sizes, int n_in,
                              void* d_out, int out_size, void* d_ws, size_t ws_size,
                              hipStream_t stream) {
    const float* x          = (const float*)d_in[0];
    const float* A          = (const float*)d_in[1];
    const float* log_lambda = (const float*)d_in[2];
    const float* W          = (const float*)d_in[3];
    const float* bvec       = (const float*)d_in[4];
    float* out              = (float*)d_out;

    const int n_pos = in_sizes[0] / DIM; // B*S = 2048
    const size_t ab16_bytes = (size_t)4 * DIM * 8 * sizeof(unsigned short);
    const size_t need = ab16_bytes + (size_t)n_pos * 32 * sizeof(float);

    if (ws_size >= need) {
        unsigned short* ab16 = (unsigned short*)d_ws;
        float* sw2 = (float*)((char*)d_ws + ab16_bytes);
        build_sw2_kernel<<<n_pos + 1, 256, 0, stream>>>(x, A, W, bvec, sw2, ab16, n_pos);
        store_g_half<<<n_pos * 2, 128, 0, stream>>>(ab16, sw2, log_lambda, out);
    } else {
        riemannian_metric_fallback<<<n_pos, 256, 0, stream>>>(x, A, log_lambda, W, bvec, out);
    }
}

// Round 20
// 113.932 us; speedup vs baseline: 1.0812x; 1.0518x over previous
//
#include <hip/hip_runtime.h>
#include <math.h>

// RiemannianMetric: g[b,s,i,j] = sum_r tanh(x·W[r]+b[r])^2 A[r,i]A[r,j] + lam*I
// B=2 S=1024 DIM=256 RANK=32. Output 537 MB f32 -> store floor ~80us @6.7TB/s.
// R20: FINAL A/B — R17 (best, 114us: dense 1KB-row stores, 4-wave blocks,
// 8 waves/CU) with PLAIN cached stores instead of nt. The only unmeasured cell
// in the store-mode x layout matrix: R8/R10's plain losses were on strided /
// half-density layouts; dense full-line rows are where L2 writeback coalescing
// could win (fillBuffer = plain + dense = 6.7 TB/s). Single-line change vs R17.

constexpr int DIM = 256;

typedef float f32x4 __attribute__((ext_vector_type(4)));
typedef short s16x8 __attribute__((ext_vector_type(8))); // 8 bf16 = 4 VGPR

static __device__ __forceinline__ unsigned short f2bf(float f) {
    unsigned int u = __builtin_bit_cast(unsigned int, f);
    u = (u + 0x7FFFu + ((u >> 16) & 1u)) >> 16; // RNE
    return (unsigned short)u;
}
static __device__ __forceinline__ float bf2f(unsigned short s) {
    return __builtin_bit_cast(float, (unsigned int)s << 16);
}

// ---------------- Kernel 1: sw2 (tanh^2) + one-time A bf16 slabs -------------
__global__ __launch_bounds__(256) void build_sw2_kernel(
    const float* __restrict__ x, const float* __restrict__ A,
    const float* __restrict__ W, const float* __restrict__ bvec,
    float* __restrict__ sw2, unsigned short* __restrict__ ab16, int n_pos)
{
    const int tid = threadIdx.x, b = blockIdx.x;

    if (b == n_pos) { // ab16[kg][j][e] = bf16(A[kg*8+e][j])
        #pragma unroll
        for (int kg = 0; kg < 4; ++kg) {
            s16x8 pk;
            #pragma unroll
            for (int e = 0; e < 8; ++e)
                pk[e] = (short)f2bf(A[(kg * 8 + e) * DIM + tid]);
            *(s16x8*)&ab16[((size_t)kg * DIM + tid) * 8] = pk;
        }
        return;
    }

    __shared__ float xs[DIM];
    xs[tid] = x[(size_t)b * DIM + tid];
    __syncthreads();

    const int r = tid >> 3, seg = tid & 7;
    const f32x4* wr4 = (const f32x4*)(W + r * DIM + seg * 32);
    const f32x4* xr4 = (const f32x4*)(xs + seg * 32);
    float dot = 0.f;
    #pragma unroll
    for (int qq = 0; qq < 8; ++qq) {
        f32x4 wv = wr4[qq], xv = xr4[qq];
        dot = fmaf(wv.x, xv.x, dot);
        dot = fmaf(wv.y, xv.y, dot);
        dot = fmaf(wv.z, xv.z, dot);
        dot = fmaf(wv.w, xv.w, dot);
    }
    dot += __shfl_xor(dot, 1);
    dot += __shfl_xor(dot, 2);
    dot += __shfl_xor(dot, 4);
    if (seg == 0) {
        float m = tanhf(dot + bvec[r]);
        sw2[(size_t)b * 32 + r] = m * m;
    }
}

// ---------------- Kernel 2: full-width-stage streamer (PLAIN stores) ---------
__global__ __launch_bounds__(256) void store_g_fullrow(
    const unsigned short* __restrict__ ab16, // [4][256][8] plain A bf16
    const float* __restrict__ sw2,           // [n_pos][32]
    const float* __restrict__ log_lambda,
    float* __restrict__ out)
{
    __shared__ alignas(16) float stage[4][16 * 256]; // 16KB per wave, 64KB total

    const int tid  = threadIdx.x;
    const int pos  = blockIdx.x;
    const int lane = tid & 63;
    const int rs   = tid >> 6;          // wave: rows 64rs..64rs+63
    const int kg   = lane >> 4, cl = lane & 15;

    const unsigned short* abase = ab16 + (size_t)kg * DIM * 8;

    // per-position scale w2[kg*8+e] (L2-resident)
    const float* w2p = sw2 + (size_t)pos * 32 + kg * 8;
    f32x4 w2lo = *(const f32x4*)w2p;
    f32x4 w2hi = *(const f32x4*)(w2p + 4);
    float w2v[8] = {w2lo.x, w2lo.y, w2lo.z, w2lo.w, w2hi.x, w2hi.y, w2hi.z, w2hi.w};

    // afr: scaled row-tile frags (32 unpack-mul-cvt per lane per position)
    s16x8 afr[4];
    #pragma unroll
    for (int t = 0; t < 4; ++t) {
        s16x8 ar = *(const s16x8*)&abase[(size_t)((4 * rs + t) * 16 + cl) * 8];
        #pragma unroll
        for (int e = 0; e < 8; ++e)
            afr[t][e] = (short)f2bf(w2v[e] * bf2f((unsigned short)ar[e]));
    }

    // bfr: all 16 plain-A col-tile frags, loaded once per position (L1-hot)
    s16x8 bfr[16];
    #pragma unroll
    for (int u = 0; u < 16; ++u)
        bfr[u] = *(const s16x8*)&abase[(size_t)(u * 16 + cl) * 8];

    const float lam = expf(log_lambda[0]);
    const bool on_diag_lane = (kg == (cl >> 2));
    const int  diag_slot    = cl & 3;

    float* sbuf = stage[rs];
    const int wbase = cl * 256 + 4 * kg;   // write: row=cl, col=u*16+4kg
    const int wswz  = (cl & 7) << 2;
    const int rcol  = lane * 4;            // read: full 1KB row / instruction

    float* gbase = out + (size_t)pos * DIM * DIM;

    #pragma unroll 1
    for (int t = 0; t < 4; ++t) {
        // 16 MFMAs -> full 16x256 tile into swizzled stage
        #pragma unroll
        for (int u = 0; u < 16; ++u) {
            f32x4 acc = (f32x4)(0.f);
            acc = __builtin_amdgcn_mfma_f32_16x16x32_bf16(bfr[u], afr[t], acc, 0, 0, 0);
            if (u == rs * 4 + t && on_diag_lane) // diagonal tile of G
                acc[diag_slot] += lam;
            *(f32x4*)&sbuf[(wbase + u * 16) ^ wswz] = acc;
        }
        // 16 full-row reads -> 16 contiguous 1KB PLAIN stores (the ONLY change)
        float* trow = gbase + (size_t)(rs * 64 + t * 16) * DIM;
        #pragma unroll
        for (int m = 0; m < 16; ++m) {
            f32x4 v = *(const f32x4*)&sbuf[(m * 256 + rcol) ^ ((m & 7) << 2)];
            *(f32x4*)(trow + (size_t)m * DIM + rcol) = v;
        }
    }
}

// ---------------- Fallback monolith (R7-validated) ---------------------------
__global__ __launch_bounds__(256, 2) void riemannian_metric_fallback(
    const float* __restrict__ x, const float* __restrict__ A,
    const float* __restrict__ log_lambda, const float* __restrict__ W,
    const float* __restrict__ bvec, float* __restrict__ out)
{
    __shared__ float xs[DIM];
    __shared__ float sw[32];
    __shared__ alignas(16) unsigned short vt[4][DIM][8];
    __shared__ alignas(16) float stage[4][16 * 128];

    const int tid  = threadIdx.x;
    const int pos  = blockIdx.x;
    const int lane = tid & 63;
    const int rs   = tid >> 6;

    xs[tid] = x[(size_t)pos * DIM + tid];
    __syncthreads();
    {
        const int r = tid >> 3, seg = tid & 7;
        const f32x4* wr4 = (const f32x4*)(W + r * DIM + seg * 32);
        const f32x4* xr4 = (const f32x4*)(xs + seg * 32);
        float dot = 0.f;
        #pragma unroll
        for (int qq = 0; qq < 8; ++qq) {
            f32x4 wv = wr4[qq], xv = xr4[qq];
            dot = fmaf(wv.x, xv.x, dot);
            dot = fmaf(wv.y, xv.y, dot);
            dot = fmaf(wv.z, xv.z, dot);
            dot = fmaf(wv.w, xv.w, dot);
        }
        dot += __shfl_xor(dot, 1);
        dot += __shfl_xor(dot, 2);
        dot += __shfl_xor(dot, 4);
        if (seg == 0) sw[r] = tanhf(dot + bvec[r]);
    }
    __syncthreads();
    #pragma unroll
    for (int g = 0; g < 4; ++g) {
        s16x8 pk;
        #pragma unroll
        for (int e = 0; e < 8; ++e) {
            const int k = g * 8 + e;
            pk[e] = (short)f2bf(sw[k] * A[k * DIM + tid]);
        }
        *(s16x8*)&vt[g][tid][0] = pk;
    }
    __syncthreads();

    const int kg = lane >> 4, cl = lane & 15;
    s16x8 bfr[16];
    #pragma unroll
    for (int u = 0; u < 16; ++u)
        bfr[u] = *(const s16x8*)&vt[kg][u * 16 + cl][0];
    s16x8 afr[4];
    #pragma unroll
    for (int t = 0; t < 4; ++t)
        afr[t] = *(const s16x8*)&vt[kg][rs * 64 + t * 16 + cl][0];

    const float lam = expf(log_lambda[0]);
    const bool on_diag_lane = (kg == (cl >> 2));
    const int  diag_slot    = cl & 3;

    float* sbuf = stage[rs];
    const int wbase = cl * 128 + 4 * kg;
    const int wswz  = (cl & 7) << 2;
    const int rrow0 = lane >> 5;
    const int rcol  = (lane & 31) * 4;
    float* gbase = out + (size_t)pos * DIM * DIM;

    #pragma unroll 1
    for (int t = 0; t < 4; ++t) {
        #pragma unroll 1
        for (int half = 0; half < 2; ++half) {
            #pragma unroll
            for (int uu = 0; uu < 8; ++uu) {
                const int u = half * 8 + uu;
                f32x4 acc = (f32x4)(0.f);
                acc = __builtin_amdgcn_mfma_f32_16x16x32_bf16(bfr[u], afr[t], acc, 0, 0, 0);
                if (u == rs * 4 + t && on_diag_lane)
                    acc[diag_slot] += lam;
                *(f32x4*)&sbuf[(wbase + uu * 16) ^ wswz] = acc;
            }
            #pragma unroll
            for (int m = 0; m < 8; ++m) {
                const int row = 2 * m + rrow0;
                f32x4 v = *(const f32x4*)&sbuf[(row * 128 + rcol) ^ ((row & 7) << 2)];
                float* gp = gbase + (size_t)(rs * 64 + t * 16 + row) * DIM
                                  + half * 128 + rcol;
                __builtin_nontemporal_store(v, (f32x4*)gp);
            }
        }
    }
}

extern "C" void kernel_launch(void* const* d_in, const int* in_sizes, int n_in,
                              void* d_out, int out_size, void* d_ws, size_t ws_size,
                              hipStream_t stream) {
    const float* x          = (const float*)d_in[0];
    const float* A          = (const float*)d_in[1];
    const float* log_lambda = (const float*)d_in[2];
    const float* W          = (const float*)d_in[3];
    const float* bvec       = (const float*)d_in[4];
    float* out              = (float*)d_out;

    const int n_pos = in_sizes[0] / DIM; // B*S = 2048
    const size_t ab16_bytes = (size_t)4 * DIM * 8 * sizeof(unsigned short);
    const size_t need = ab16_bytes + (size_t)n_pos * 32 * sizeof(float);

    if (ws_size >= need) {
        unsigned short* ab16 = (unsigned short*)d_ws;
        float* sw2 = (float*)((char*)d_ws + ab16_bytes);
        build_sw2_kernel<<<n_pos + 1, 256, 0, stream>>>(x, A, W, bvec, sw2, ab16, n_pos);
        store_g_fullrow<<<n_pos, 256, 0, stream>>>(ab16, sw2, log_lambda, out);
    } else {
        riemannian_metric_fallback<<<n_pos, 256, 0, stream>>>(x, A, log_lambda, W, bvec, out);
    }
}